// Round 7
// baseline (180.990 us; speedup 1.0000x reference)
//
#include <hip/hip_runtime.h>
#include <hip/hip_bf16.h>

typedef short s8v __attribute__((ext_vector_type(8)));   // 8 bf16 (4 VGPRs) MFMA A/B frag
typedef float f4v __attribute__((ext_vector_type(4)));   // 4 fp32 MFMA C/D frag

__device__ __forceinline__ unsigned int bfround(float f) {
    unsigned int x = __float_as_uint(f);
    return (x + 0x7fffu + ((x >> 16) & 1u)) >> 16;  // RNE fp32->bf16
}
// packed RNE fp32x2 -> bf16x2 (v_cvt_pk_bf16_f32 on gfx950)
__device__ __forceinline__ unsigned int pkbf(float x, float y) {
    __hip_bfloat162 h = __float22bfloat162_rn(make_float2(x, y));
    return *(unsigned int*)&h;
}
// signed-int8 extract byte k of word w -> float  (v_bfe_i32 + v_cvt_f32_i32)
__device__ __forceinline__ float i8f(unsigned int w, int k) {
    return (float)((int)(signed char)(w >> (8 * k)));
}

// Pack W1 (fp32, [256x128]) into bf16 MFMA B-fragments laid out per-lane so proj
// waves read them with fully-coalesced uint4 loads.
// WF[half][c][t][lane] : uint4 = 8 bf16, j=0..7, k = c*32 + (lane>>4)*8 + j, col = t*16 + (lane&15)
// v12: separate kernel again — v11's inlined per-block pack regressed proj
// 41->51us (64KB W1 re-read x1024 blocks through the feature-stream L2 sets,
// +20 VGPR on the whole kernel, LDS write contention under the tile-0 DMA).
__global__ __launch_bounds__(256) void pack_w(const float* __restrict__ W1,
                                              uint4* __restrict__ WF)
{
    const int half = blockIdx.x;
    #pragma unroll
    for (int iter = 0; iter < 8; ++iter) {
        int idx  = iter * 256 + threadIdx.x;   // (c,t,lane) flattened
        int lane = idx & 63;
        int t    = (idx >> 6) & 7;
        int c    = idx >> 9;
        int q = lane >> 4, m = lane & 15;
        unsigned int w[4];
        #pragma unroll
        for (int jj = 0; jj < 4; ++jj) {
            float lo = W1[(size_t)(half * 128 + c * 32 + q * 8 + 2 * jj    ) * 128 + t * 16 + m];
            float hi = W1[(size_t)(half * 128 + c * 32 + q * 8 + 2 * jj + 1) * 128 + t * 16 + m];
            w[jj] = bfround(lo) | (bfround(hi) << 16);
        }
        WF[(size_t)half * 2048 + idx] = make_uint4(w[0], w[1], w[2], w[3]);
    }
}

// Projection v12 == v10 (proven 0-conflict, ~41us): fully-coalesced feature
// DMA; each of the 8 global_load_lds per tile reads a contiguous fully-covered
// 1KB; LDS image row-major with byte-swizzle o ^= (row&7)<<4 (linear dest +
// inverse-swizzled SOURCE + swizzle on READ) -> A-pulls bank-uniform. One
// covered vmcnt wait per tile. 4 waves/block, LDS = 32KB W + 4x8KB A = 64KB
// -> 2 blocks/CU, 8 waves/CU. Blocks [0,bph)=users, [bph,2bph)=movies.
// int8 rows + per-row fp32 scale, column perm(t*16+m) = m*8+t.
__global__ __launch_bounds__(256, 2) void proj_kernel(
    const float* __restrict__ userf, const float* __restrict__ movief,
    const uint4* __restrict__ WF, const float* __restrict__ b1,
    uint2* __restrict__ Pu, uint2* __restrict__ Pm,
    float* __restrict__ SU, float* __restrict__ SM,
    int ntiles, int bph)
{
    __shared__ uint4 wlds[2048];       // 32KB: this half's 32 W-fragments
    __shared__ uint4 alds[4][512];     // 32KB: 8KB/wave A staging (swizzled rows)

    const int half = blockIdx.x >= bph;
    const int bid  = half ? blockIdx.x - bph : blockIdx.x;
    const float* __restrict__ feat = half ? movief : userf;
    uint2* __restrict__ P = half ? Pm : Pu;
    float* __restrict__ S = half ? SM : SU;
    const uint4* __restrict__ wfh = WF + (size_t)half * 2048;

    // Cooperative W fill: 2048 uint4 / 256 threads = 8 each.
    #pragma unroll
    for (int i = 0; i < 8; ++i)
        wlds[i * 256 + threadIdx.x] = wfh[i * 256 + threadIdx.x];

    const int lane = threadIdx.x & 63;
    const int wv   = threadIdx.x >> 6;
    const int m    = lane & 15;
    const int q    = lane >> 4;

    const int wid = bid * 4 + wv;   // wave id within half
    const int nw  = bph * 4;        // waves per half

    float bias_v[8];
    #pragma unroll
    for (int t = 0; t < 8; ++t)
        bias_v[t] = half ? b1[t * 16 + m] : 0.0f;

    // DMA addressing: tile = 16 rows x 512B = 8KB. Instruction j stages rows
    // {2j, 2j+1}: lanes 0-31 -> row 2j, lanes 32-63 -> row 2j+1; within a row
    // lane reads 16B at ((lane&31)*16) ^ ((row&7)<<4) (inverse swizzle; a
    // permutation within 128B groups -> full-line coalesced). LDS dest is
    // linear, so LDS[row*512 + (o ^ swz(row))] holds global row byte o.
    const char* gfeat  = (const char*)feat;
    const int   rhalf  = lane >> 5;          // which of the 2 rows this lane serves
    const int   l31x16 = (lane & 31) * 16;   // linear 16B chunk within the row

#define ISSUE_ALL(t_) do {                                                     \
        const char* gb_ = gfeat + (size_t)(t_) * 8192;                         \
        _Pragma("unroll")                                                      \
        for (int j_ = 0; j_ < 8; ++j_) {                                       \
            const int r_ = 2 * j_ + rhalf;                                     \
            const size_t so_ = (size_t)r_ * 512 + (size_t)(l31x16 ^ ((r_ & 7) << 4)); \
            __builtin_amdgcn_global_load_lds(                                  \
                (const __attribute__((address_space(1))) void*)(gb_ + so_),    \
                (__attribute__((address_space(3))) void*)&alds[wv][j_ * 64],   \
                16, 0, 0);                                                     \
        }                                                                      \
    } while (0)

    // A-pull: frag (c,h) for lane (m,q) lives at LDS uint4 index
    // m*32 + ((c*8 + q*2 + h) ^ (m&7))  (byte m*512 + (c*128+q*32+h*16)^swz).
    const int swz = m & 7;
#define APULL(c_, h_) alds[wv][m * 32 + (((c_) * 8 + q * 2 + (h_)) ^ swz)]

// two staged float4 (h0,h1) -> one bf16x8 A-frag (v7 CVT_A order)
#define CVT2(p0, p1, dst) do {                                                 \
        uint4 aw_;                                                             \
        const float4 f0_ = *(const float4*)&(p0);                              \
        const float4 f1_ = *(const float4*)&(p1);                              \
        aw_.x = pkbf(f0_.x, f0_.y); aw_.y = pkbf(f0_.z, f0_.w);                \
        aw_.z = pkbf(f1_.x, f1_.y); aw_.w = pkbf(f1_.z, f1_.w);                \
        dst = *(const s8v*)&aw_;                                               \
    } while (0)

#define MFMA_C(c_, afv) do {                                                   \
        _Pragma("unroll")                                                      \
        for (int t_ = 0; t_ < 8; ++t_) {                                       \
            uint4 wf_ = wlds[((c_) * 8 + t_) * 64 + lane];                     \
            acc[t_] = __builtin_amdgcn_mfma_f32_16x16x32_bf16(                 \
                afv, *(const s8v*)&wf_, acc[t_], 0, 0, 0);                     \
        }                                                                      \
    } while (0)

#define WAIT_VM0()   do { asm volatile("s_waitcnt vmcnt(0)" ::: "memory");  \
                          __builtin_amdgcn_sched_barrier(0); } while (0)
#define WAIT_LGKM0() do { asm volatile("s_waitcnt lgkmcnt(0)" ::: "memory"); \
                          __builtin_amdgcn_sched_barrier(0); } while (0)

    int tile = wid;
    if (tile < ntiles) ISSUE_ALL(tile);   // prefetch tile 0; __syncthreads drains it

    __syncthreads();   // W visible to all waves (also completes prologue DMA)

    while (tile < ntiles) {
        const int nxt = tile + nw;

        f4v acc[8];
        #pragma unroll
        for (int t = 0; t < 8; ++t)
            acc[t] = (f4v){bias_v[t], bias_v[t], bias_v[t], bias_v[t]};

        WAIT_VM0();                                 // tile fully staged
        uint4 p0 = APULL(0, 0), p1 = APULL(0, 1);
        uint4 p2 = APULL(1, 0), p3 = APULL(1, 1);
        uint4 p4 = APULL(2, 0), p5 = APULL(2, 1);
        uint4 p6 = APULL(3, 0), p7 = APULL(3, 1);
        s8v af0, af1, af2, af3;
        CVT2(p0, p1, af0);
        CVT2(p2, p3, af1);
        CVT2(p4, p5, af2);
        CVT2(p6, p7, af3);
        WAIT_LGKM0();                               // pulls retired -> slots free
        if (nxt < ntiles) ISSUE_ALL(nxt);           // 8KB in flight under ALL compute below

        MFMA_C(0, af0);
        MFMA_C(1, af1);
        MFMA_C(2, af2);
        MFMA_C(3, af3);

        // C/D layout: col = t*16+m, row = q*4+r  [m89/m91 verified]. int8-quantize
        // each row; absmax over the 16-lane m-group (xor 1..8 stays in-group).
        #pragma unroll
        for (int r = 0; r < 4; ++r) {
            float mx = 0.0f;
            #pragma unroll
            for (int t = 0; t < 8; ++t) mx = fmaxf(mx, fabsf(acc[t][r]));
            #pragma unroll
            for (int off = 1; off < 16; off <<= 1)
                mx = fmaxf(mx, __shfl_xor(mx, off, 64));
            float inv = mx > 0.0f ? 127.0f / mx : 0.0f;

            unsigned int lo = 0, hi = 0;
            #pragma unroll
            for (int t = 0; t < 4; ++t) {
                lo |= ((unsigned int)(__float2int_rn(acc[t][r]     * inv) & 0xff)) << (8 * t);
                hi |= ((unsigned int)(__float2int_rn(acc[t + 4][r] * inv) & 0xff)) << (8 * t);
            }
            int row = tile * 16 + q * 4 + r;
            P[(size_t)row * 16 + m] = make_uint2(lo, hi);  // 16 lanes x 8B = one 128B row
            if (m == 0) S[row] = mx * (1.0f / 127.0f);
        }

        tile = nxt;
    }
#undef ISSUE_ALL
#undef APULL
#undef CVT2
#undef MFMA_C
#undef WAIT_VM0
#undef WAIT_LGKM0
}

// out[e] = relu(su*Qu[src] + sm*Qm[dst]) . W2 + b2   (b1 folded into Pm; perm'd dims)
// v12 == v11 edge (proven ~34us, was 42): 8 edges per 16-lane group -> 16
// row-gathers + 16 scale-gathers in flight per wave (latency-concurrency fix,
// confirmed by r6: edge left the top-5). 16 lanes/edge, uint2 = 8 int8 dims.
__global__ __launch_bounds__(256) void edge_kernel(
    const int* __restrict__ src, const int* __restrict__ dst,
    const uint2* __restrict__ Pu, const uint2* __restrict__ Pm,
    const float* __restrict__ SU, const float* __restrict__ SM,
    const float* __restrict__ W2, const float* __restrict__ b2,
    float* __restrict__ out, int E)
{
    const int lane = threadIdx.x & 63;
    const int L    = lane & 15;      // sub-lane within edge group
    const int g    = lane >> 4;      // edge group 0..3
    const int eg   = ((blockIdx.x * 4 + (threadIdx.x >> 6)) * 4 + g) * 8;

    // W2 at perm position L*8+j is original col j*16+L
    float w2v[8];
    #pragma unroll
    for (int j = 0; j < 8; ++j) w2v[j] = W2[j * 16 + L];

    if (eg + 8 <= E) {
        int si[8], di[8];
        #pragma unroll
        for (int i = 0; i < 8; ++i) { si[i] = src[eg + i]; di[i] = dst[eg + i]; }

        uint2 pu[8], pm[8];
        float scu[8], scm[8];
        #pragma unroll
        for (int i = 0; i < 8; ++i) {
            pu[i] = Pu[(size_t)si[i] * 16 + L];   // 8B/lane, one 128B line per 16-lane group
            pm[i] = Pm[(size_t)di[i] * 16 + L];
            scu[i] = SU[si[i]];                   // 400KB arrays, mostly L2/L3-resident
            scm[i] = SM[di[i]];
        }

        float res[8];
        #pragma unroll
        for (int i = 0; i < 8; ++i) {
            const unsigned int uw[2] = {pu[i].x, pu[i].y};
            const unsigned int mw[2] = {pm[i].x, pm[i].y};
            float acc = 0.0f;
            #pragma unroll
            for (int v = 0; v < 2; ++v) {
                #pragma unroll
                for (int k = 0; k < 4; ++k) {
                    float h = fmaf(scu[i], i8f(uw[v], k), scm[i] * i8f(mw[v], k));
                    acc = fmaf(fmaxf(h, 0.0f), w2v[v * 4 + k], acc);
                }
            }
            #pragma unroll
            for (int off = 1; off < 16; off <<= 1)
                acc += __shfl_xor(acc, off, 64);
            res[i] = acc;
        }

        if (L == 0) {
            float bb = b2[0];
            *(float4*)(out + eg)     = make_float4(res[0] + bb, res[1] + bb, res[2] + bb, res[3] + bb);
            *(float4*)(out + eg + 4) = make_float4(res[4] + bb, res[5] + bb, res[6] + bb, res[7] + bb);
        }
    } else if (eg < E) {
        // tail (unused when E % 8 == 0; kept for safety)
        for (int i = 0; i < 8; ++i) {
            int e = eg + i;
            if (e >= E) break;
            int s = src[e], d = dst[e];
            uint2 pue = Pu[(size_t)s * 16 + L];
            uint2 pme = Pm[(size_t)d * 16 + L];
            float su = SU[s], sm = SM[d];
            const unsigned int uw[2] = {pue.x, pue.y};
            const unsigned int mw[2] = {pme.x, pme.y};
            float acc = 0.0f;
            #pragma unroll
            for (int v = 0; v < 2; ++v)
                #pragma unroll
                for (int k = 0; k < 4; ++k) {
                    float h = fmaf(su, i8f(uw[v], k), sm * i8f(mw[v], k));
                    acc = fmaf(fmaxf(h, 0.0f), w2v[v * 4 + k], acc);
                }
            #pragma unroll
            for (int off = 1; off < 16; off <<= 1)
                acc += __shfl_xor(acc, off, 64);
            if (L == 0) out[e] = acc + b2[0];
        }
    }
}

extern "C" void kernel_launch(void* const* d_in, const int* in_sizes, int n_in,
                              void* d_out, int out_size, void* d_ws, size_t ws_size,
                              hipStream_t stream) {
    const float* userf  = (const float*)d_in[0];
    const float* movief = (const float*)d_in[1];
    const int*   eidx   = (const int*)d_in[2];
    const float* W1     = (const float*)d_in[3];
    const float* b1     = (const float*)d_in[4];
    const float* W2     = (const float*)d_in[5];
    const float* b2     = (const float*)d_in[6];
    float* out = (float*)d_out;

    const int NU = in_sizes[0] / 128;   // 100000
    const int NM = in_sizes[1] / 128;   // 100000
    const int E  = in_sizes[2] / 2;     // 1000000

    // Workspace: Qu 12.8MB | Qm 12.8MB | SU 400KB | SM 400KB | WF 64KB
    uint2* Pu = (uint2*)d_ws;
    uint2* Pm = Pu + (size_t)NU * 16;
    float* SU = (float*)(Pm + (size_t)NM * 16);
    float* SM = SU + NU;
    uint4* WF = (uint4*)(SM + NM);

    const int ntiles = NU / 16;   // 6250 per half
    const int bph    = 512;       // 2048 waves/half (4 waves/block), 2 blocks/CU

    pack_w<<<2, 256, 0, stream>>>(W1, WF);
    proj_kernel<<<2 * bph, 256, 0, stream>>>(userf, movief, WF, b1, Pu, Pm, SU, SM, ntiles, bph);
    edge_kernel<<<(E + 127) / 128, 256, 0, stream>>>(eidx, eidx + E, Pu, Pm, SU, SM, W2, b2, out, E);
}

// Round 8
// 180.270 us; speedup vs baseline: 1.0040x; 1.0040x over previous
//
#include <hip/hip_runtime.h>
#include <hip/hip_bf16.h>

typedef short s8v __attribute__((ext_vector_type(8)));   // 8 bf16 (4 VGPRs) MFMA A/B frag
typedef float f4v __attribute__((ext_vector_type(4)));   // 4 fp32 MFMA C/D frag

__device__ __forceinline__ unsigned int bfround(float f) {
    unsigned int x = __float_as_uint(f);
    return (x + 0x7fffu + ((x >> 16) & 1u)) >> 16;  // RNE fp32->bf16
}
// packed RNE fp32x2 -> bf16x2 (v_cvt_pk_bf16_f32 on gfx950)
__device__ __forceinline__ unsigned int pkbf(float x, float y) {
    __hip_bfloat162 h = __float22bfloat162_rn(make_float2(x, y));
    return *(unsigned int*)&h;
}
// biased-uint8 extract byte k of word w -> float (single v_cvt_f32_ubyteN)
__device__ __forceinline__ float ub2f(unsigned int w, int k) {
    return (float)((w >> (8 * k)) & 0xffu);
}

// Pack W1 (fp32, [256x128]) into bf16 MFMA B-fragments laid out per-lane so proj
// waves read them with fully-coalesced uint4 loads.
// WF[half][c][t][lane] : uint4 = 8 bf16, j=0..7, k = c*32 + (lane>>4)*8 + j, col = t*16 + (lane&15)
__global__ __launch_bounds__(256) void pack_w(const float* __restrict__ W1,
                                              uint4* __restrict__ WF)
{
    const int half = blockIdx.x;
    #pragma unroll
    for (int iter = 0; iter < 8; ++iter) {
        int idx  = iter * 256 + threadIdx.x;   // (c,t,lane) flattened
        int lane = idx & 63;
        int t    = (idx >> 6) & 7;
        int c    = idx >> 9;
        int q = lane >> 4, m = lane & 15;
        unsigned int w[4];
        #pragma unroll
        for (int jj = 0; jj < 4; ++jj) {
            float lo = W1[(size_t)(half * 128 + c * 32 + q * 8 + 2 * jj    ) * 128 + t * 16 + m];
            float hi = W1[(size_t)(half * 128 + c * 32 + q * 8 + 2 * jj + 1) * 128 + t * 16 + m];
            w[jj] = bfround(lo) | (bfround(hi) << 16);
        }
        WF[(size_t)half * 2048 + idx] = make_uint4(w[0], w[1], w[2], w[3]);
    }
}

// Projection v13 == v10 structure (proven 0-conflict ~41us): fully-coalesced
// feature DMA (8 contiguous 1KB global_load_lds per tile), LDS image row-major
// with byte-swizzle o ^= (row&7)<<4 (linear dest + inverse-swizzled SOURCE +
// swizzle on READ) -> bank-uniform A-pulls. One covered vmcnt wait per tile.
// 4 waves/block, LDS = 32KB W + 4x8KB A = 64KB -> 2 blocks/CU, 8 waves/CU.
// v13 change: quantized rows stored as BIASED UINT8 (v+128) so the edge kernel
// decodes with 1-op v_cvt_f32_ubyteN instead of bfe+cvt_i32. Quantization is
// bit-identical: RNE(y+128) == RNE(y)+128 (even-integer shift, exact in fp32).
// Blocks [0,bph)=users, [bph,2bph)=movies. column perm(t*16+m) = m*8+t.
__global__ __launch_bounds__(256, 2) void proj_kernel(
    const float* __restrict__ userf, const float* __restrict__ movief,
    const uint4* __restrict__ WF, const float* __restrict__ b1,
    uint2* __restrict__ Pu, uint2* __restrict__ Pm,
    float* __restrict__ SU, float* __restrict__ SM,
    int ntiles, int bph)
{
    __shared__ uint4 wlds[2048];       // 32KB: this half's 32 W-fragments
    __shared__ uint4 alds[4][512];     // 32KB: 8KB/wave A staging (swizzled rows)

    const int half = blockIdx.x >= bph;
    const int bid  = half ? blockIdx.x - bph : blockIdx.x;
    const float* __restrict__ feat = half ? movief : userf;
    uint2* __restrict__ P = half ? Pm : Pu;
    float* __restrict__ S = half ? SM : SU;
    const uint4* __restrict__ wfh = WF + (size_t)half * 2048;

    // Cooperative W fill: 2048 uint4 / 256 threads = 8 each.
    #pragma unroll
    for (int i = 0; i < 8; ++i)
        wlds[i * 256 + threadIdx.x] = wfh[i * 256 + threadIdx.x];

    const int lane = threadIdx.x & 63;
    const int wv   = threadIdx.x >> 6;
    const int m    = lane & 15;
    const int q    = lane >> 4;

    const int wid = bid * 4 + wv;   // wave id within half
    const int nw  = bph * 4;        // waves per half

    float bias_v[8];
    #pragma unroll
    for (int t = 0; t < 8; ++t)
        bias_v[t] = half ? b1[t * 16 + m] : 0.0f;

    // DMA addressing: tile = 16 rows x 512B = 8KB. Instruction j stages rows
    // {2j, 2j+1}: lanes 0-31 -> row 2j, lanes 32-63 -> row 2j+1; within a row
    // lane reads 16B at ((lane&31)*16) ^ ((row&7)<<4) (inverse swizzle; a
    // permutation within 128B groups -> full-line coalesced). LDS dest is
    // linear, so LDS[row*512 + (o ^ swz(row))] holds global row byte o.
    const char* gfeat  = (const char*)feat;
    const int   rhalf  = lane >> 5;          // which of the 2 rows this lane serves
    const int   l31x16 = (lane & 31) * 16;   // linear 16B chunk within the row

#define ISSUE_ALL(t_) do {                                                     \
        const char* gb_ = gfeat + (size_t)(t_) * 8192;                         \
        _Pragma("unroll")                                                      \
        for (int j_ = 0; j_ < 8; ++j_) {                                       \
            const int r_ = 2 * j_ + rhalf;                                     \
            const size_t so_ = (size_t)r_ * 512 + (size_t)(l31x16 ^ ((r_ & 7) << 4)); \
            __builtin_amdgcn_global_load_lds(                                  \
                (const __attribute__((address_space(1))) void*)(gb_ + so_),    \
                (__attribute__((address_space(3))) void*)&alds[wv][j_ * 64],   \
                16, 0, 0);                                                     \
        }                                                                      \
    } while (0)

    // A-pull: frag (c,h) for lane (m,q) lives at LDS uint4 index
    // m*32 + ((c*8 + q*2 + h) ^ (m&7))  (byte m*512 + (c*128+q*32+h*16)^swz).
    const int swz = m & 7;
#define APULL(c_, h_) alds[wv][m * 32 + (((c_) * 8 + q * 2 + (h_)) ^ swz)]

// two staged float4 (h0,h1) -> one bf16x8 A-frag (v7 CVT_A order)
#define CVT2(p0, p1, dst) do {                                                 \
        uint4 aw_;                                                             \
        const float4 f0_ = *(const float4*)&(p0);                              \
        const float4 f1_ = *(const float4*)&(p1);                              \
        aw_.x = pkbf(f0_.x, f0_.y); aw_.y = pkbf(f0_.z, f0_.w);                \
        aw_.z = pkbf(f1_.x, f1_.y); aw_.w = pkbf(f1_.z, f1_.w);                \
        dst = *(const s8v*)&aw_;                                               \
    } while (0)

#define MFMA_C(c_, afv) do {                                                   \
        _Pragma("unroll")                                                      \
        for (int t_ = 0; t_ < 8; ++t_) {                                       \
            uint4 wf_ = wlds[((c_) * 8 + t_) * 64 + lane];                     \
            acc[t_] = __builtin_amdgcn_mfma_f32_16x16x32_bf16(                 \
                afv, *(const s8v*)&wf_, acc[t_], 0, 0, 0);                     \
        }                                                                      \
    } while (0)

#define WAIT_VM0()   do { asm volatile("s_waitcnt vmcnt(0)" ::: "memory");  \
                          __builtin_amdgcn_sched_barrier(0); } while (0)
#define WAIT_LGKM0() do { asm volatile("s_waitcnt lgkmcnt(0)" ::: "memory"); \
                          __builtin_amdgcn_sched_barrier(0); } while (0)

    int tile = wid;
    if (tile < ntiles) ISSUE_ALL(tile);   // prefetch tile 0; __syncthreads drains it

    __syncthreads();   // W visible to all waves (also completes prologue DMA)

    while (tile < ntiles) {
        const int nxt = tile + nw;

        f4v acc[8];
        #pragma unroll
        for (int t = 0; t < 8; ++t)
            acc[t] = (f4v){bias_v[t], bias_v[t], bias_v[t], bias_v[t]};

        WAIT_VM0();                                 // tile fully staged
        uint4 p0 = APULL(0, 0), p1 = APULL(0, 1);
        uint4 p2 = APULL(1, 0), p3 = APULL(1, 1);
        uint4 p4 = APULL(2, 0), p5 = APULL(2, 1);
        uint4 p6 = APULL(3, 0), p7 = APULL(3, 1);
        s8v af0, af1, af2, af3;
        CVT2(p0, p1, af0);
        CVT2(p2, p3, af1);
        CVT2(p4, p5, af2);
        CVT2(p6, p7, af3);
        WAIT_LGKM0();                               // pulls retired -> slots free
        if (nxt < ntiles) ISSUE_ALL(nxt);           // 8KB in flight under ALL compute below

        MFMA_C(0, af0);
        MFMA_C(1, af1);
        MFMA_C(2, af2);
        MFMA_C(3, af3);

        // C/D layout: col = t*16+m, row = q*4+r  [m89/m91 verified]. Quantize
        // each row to biased uint8: byte = RNE(x*inv) + 128 computed as
        // RNE(fmaf(x, inv, 128)) — identical quantization, bias folded free.
        // absmax over the 16-lane m-group (xor 1..8 stays in-group).
        #pragma unroll
        for (int r = 0; r < 4; ++r) {
            float mx = 0.0f;
            #pragma unroll
            for (int t = 0; t < 8; ++t) mx = fmaxf(mx, fabsf(acc[t][r]));
            #pragma unroll
            for (int off = 1; off < 16; off <<= 1)
                mx = fmaxf(mx, __shfl_xor(mx, off, 64));
            float inv = mx > 0.0f ? 127.0f / mx : 0.0f;

            unsigned int lo = 0, hi = 0;
            #pragma unroll
            for (int t = 0; t < 4; ++t) {
                lo |= ((unsigned int)(__float2int_rn(fmaf(acc[t][r],     inv, 128.0f)) & 0xff)) << (8 * t);
                hi |= ((unsigned int)(__float2int_rn(fmaf(acc[t + 4][r], inv, 128.0f)) & 0xff)) << (8 * t);
            }
            int row = tile * 16 + q * 4 + r;
            P[(size_t)row * 16 + m] = make_uint2(lo, hi);  // 16 lanes x 8B = one 128B row
            if (m == 0) S[row] = mx * (1.0f / 127.0f);
        }

        tile = nxt;
    }
#undef ISSUE_ALL
#undef APULL
#undef CVT2
#undef MFMA_C
#undef WAIT_VM0
#undef WAIT_LGKM0
}

// out[e] = relu(su*(Qu[src]-128) + sm*(Qm[dst]-128)) . W2 + b2  (biased uint8;
// b1 folded into Pm; perm'd dims). v13: decode via v_cvt_f32_ubyteN (1 op/dim,
// was bfe+cvt = 2) with the -128 bias folded into off = -128*(su+sm) per edge.
// 8 edges per 16-lane group, 16 row-gathers + 16 scale-gathers in flight/wave.
// 16 lanes/edge, uint2 = 8 uint8 dims per lane.
__global__ __launch_bounds__(256) void edge_kernel(
    const int* __restrict__ src, const int* __restrict__ dst,
    const uint2* __restrict__ Pu, const uint2* __restrict__ Pm,
    const float* __restrict__ SU, const float* __restrict__ SM,
    const float* __restrict__ W2, const float* __restrict__ b2,
    float* __restrict__ out, int E)
{
    const int lane = threadIdx.x & 63;
    const int L    = lane & 15;      // sub-lane within edge group
    const int g    = lane >> 4;      // edge group 0..3
    const int eg   = ((blockIdx.x * 4 + (threadIdx.x >> 6)) * 4 + g) * 8;

    // W2 at perm position L*8+j is original col j*16+L
    float w2v[8];
    #pragma unroll
    for (int j = 0; j < 8; ++j) w2v[j] = W2[j * 16 + L];

    if (eg + 8 <= E) {
        int si[8], di[8];
        #pragma unroll
        for (int i = 0; i < 8; ++i) { si[i] = src[eg + i]; di[i] = dst[eg + i]; }

        uint2 pu[8], pm[8];
        float scu[8], scm[8];
        #pragma unroll
        for (int i = 0; i < 8; ++i) {
            pu[i] = Pu[(size_t)si[i] * 16 + L];   // 8B/lane, one 128B line per 16-lane group
            pm[i] = Pm[(size_t)di[i] * 16 + L];
            scu[i] = SU[si[i]];                   // 400KB arrays, mostly L2/L3-resident
            scm[i] = SM[di[i]];
        }

        float res[8];
        #pragma unroll
        for (int i = 0; i < 8; ++i) {
            const unsigned int uw[2] = {pu[i].x, pu[i].y};
            const unsigned int mw[2] = {pm[i].x, pm[i].y};
            const float off = -128.0f * (scu[i] + scm[i]);
            float acc = 0.0f;
            #pragma unroll
            for (int v = 0; v < 2; ++v) {
                #pragma unroll
                for (int k = 0; k < 4; ++k) {
                    float h = fmaf(scu[i], ub2f(uw[v], k),
                              fmaf(scm[i], ub2f(mw[v], k), off));
                    acc = fmaf(fmaxf(h, 0.0f), w2v[v * 4 + k], acc);
                }
            }
            #pragma unroll
            for (int off2 = 1; off2 < 16; off2 <<= 1)
                acc += __shfl_xor(acc, off2, 64);
            res[i] = acc;
        }

        if (L == 0) {
            float bb = b2[0];
            *(float4*)(out + eg)     = make_float4(res[0] + bb, res[1] + bb, res[2] + bb, res[3] + bb);
            *(float4*)(out + eg + 4) = make_float4(res[4] + bb, res[5] + bb, res[6] + bb, res[7] + bb);
        }
    } else if (eg < E) {
        // tail (unused when E % 8 == 0; kept for safety)
        for (int i = 0; i < 8; ++i) {
            int e = eg + i;
            if (e >= E) break;
            int s = src[e], d = dst[e];
            uint2 pue = Pu[(size_t)s * 16 + L];
            uint2 pme = Pm[(size_t)d * 16 + L];
            float su = SU[s], sm = SM[d];
            const unsigned int uw[2] = {pue.x, pue.y};
            const unsigned int mw[2] = {pme.x, pme.y};
            const float off = -128.0f * (su + sm);
            float acc = 0.0f;
            #pragma unroll
            for (int v = 0; v < 2; ++v)
                #pragma unroll
                for (int k = 0; k < 4; ++k) {
                    float h = fmaf(su, ub2f(uw[v], k), fmaf(sm, ub2f(mw[v], k), off));
                    acc = fmaf(fmaxf(h, 0.0f), w2v[v * 4 + k], acc);
                }
            #pragma unroll
            for (int off2 = 1; off2 < 16; off2 <<= 1)
                acc += __shfl_xor(acc, off2, 64);
            if (L == 0) out[e] = acc + b2[0];
        }
    }
}

extern "C" void kernel_launch(void* const* d_in, const int* in_sizes, int n_in,
                              void* d_out, int out_size, void* d_ws, size_t ws_size,
                              hipStream_t stream) {
    const float* userf  = (const float*)d_in[0];
    const float* movief = (const float*)d_in[1];
    const int*   eidx   = (const int*)d_in[2];
    const float* W1     = (const float*)d_in[3];
    const float* b1     = (const float*)d_in[4];
    const float* W2     = (const float*)d_in[5];
    const float* b2     = (const float*)d_in[6];
    float* out = (float*)d_out;

    const int NU = in_sizes[0] / 128;   // 100000
    const int NM = in_sizes[1] / 128;   // 100000
    const int E  = in_sizes[2] / 2;     // 1000000

    // Workspace: Qu 12.8MB | Qm 12.8MB | SU 400KB | SM 400KB | WF 64KB
    uint2* Pu = (uint2*)d_ws;
    uint2* Pm = Pu + (size_t)NU * 16;
    float* SU = (float*)(Pm + (size_t)NM * 16);
    float* SM = SU + NU;
    uint4* WF = (uint4*)(SM + NM);

    const int ntiles = NU / 16;   // 6250 per half
    const int bph    = 512;       // 2048 waves/half (4 waves/block), 2 blocks/CU

    pack_w<<<2, 256, 0, stream>>>(W1, WF);
    proj_kernel<<<2 * bph, 256, 0, stream>>>(userf, movief, WF, b1, Pu, Pm, SU, SM, ntiles, bph);
    edge_kernel<<<(E + 127) / 128, 256, 0, stream>>>(eidx, eidx + E, Pu, Pm, SU, SM, W2, b2, out, E);
}